// Round 4
// baseline (212.849 us; speedup 1.0000x reference)
//
#include <hip/hip_runtime.h>
#include <hip/hip_cooperative_groups.h>
#include <math.h>

namespace cg = cooperative_groups;

// Grid constants from the reference
#define GH 512
#define GW 512
#define GHW (GH * GW)
#define RR 3
#define SH 16            // strip height (rows of the heat grid per block)
#define SSHIFT 4
#define NSTRIP (GH / SH) // 32
#define SCAP 1024        // per-strip staged point capacity (mean ~350, 6-sigma ~460)

// Precision model (validated rounds 4-8, absmax 3.9e-3): pure f32 chain with
// multiply-by-reciprocal voxel scale (px = (x - XMIN) * 10.0f) and f32 expf.
// Do not change this arithmetic. Heatmap max is order-free (monotone int-bit
// compare on positive floats), so strip decomposition cannot perturb it.
//
// Measured constants (R0-R3): ws poison fills ~84us/iter (untouchable),
// ~10-12us per dispatch gap, heat-scan floor ~43us when every strip/tile
// block re-reads raw radar (24B/pt + transform, 32 serial iters). R2 lesson:
// never put the gather inside a coop grid (occupancy cap -> 305 GB/s).
//
// R4 structure: 2 dispatches.
//  D1 = cooperative heat kernel, natural 512-block grid (2/CU, 40KB LDS,
//       co-resident): phase 0 pre-transforms all 2M radar points once
//       (1 pt/thread) into (px,py) float2 workspace; grid.sync; phase 1
//       strip splat whose scan reads the pre-transformed slice as coalesced
//       float4 (2 pts/lane-load, no transform math, XCD-L2-resident slice).
//  D2 = fused gather (unchanged, b == blockIdx.x keeps heat XCD-local).

__device__ __forceinline__ void compute_pose(const float* __restrict__ P0,
                                             const float* __restrict__ P1,
                                             float* __restrict__ T) {
    double a00 = P1[0], a01 = P1[1], a02 = P1[2],  t1x = P1[3];
    double a10 = P1[4], a11 = P1[5], a12 = P1[6],  t1y = P1[7];
    double a20 = P1[8], a21 = P1[9], a22 = P1[10], t1z = P1[11];
    double c00 = a11 * a22 - a12 * a21;
    double c01 = a12 * a20 - a10 * a22;
    double c02 = a10 * a21 - a11 * a20;
    double det = a00 * c00 + a01 * c01 + a02 * c02;
    double id = 1.0 / det;
    double r00 = c00 * id;
    double r01 = (a02 * a21 - a01 * a22) * id;
    double r02 = (a01 * a12 - a02 * a11) * id;
    double r10 = c01 * id;
    double r11 = (a00 * a22 - a02 * a20) * id;
    double r12 = (a02 * a10 - a00 * a12) * id;
    double r20 = c02 * id;
    double r21 = (a01 * a20 - a00 * a21) * id;
    double r22 = (a00 * a11 - a01 * a10) * id;

    double b00 = P0[0], b01 = P0[1], b02 = P0[2],  t0x = P0[3];
    double b10 = P0[4], b11 = P0[5], b12 = P0[6],  t0y = P0[7];
    double b20 = P0[8], b21 = P0[9], b22 = P0[10], t0z = P0[11];
    double dx = t0x - t1x, dy = t0y - t1y, dz = t0z - t1z;

    T[0]  = (float)(r00 * b00 + r01 * b10 + r02 * b20);
    T[1]  = (float)(r00 * b01 + r01 * b11 + r02 * b21);
    T[2]  = (float)(r00 * b02 + r01 * b12 + r02 * b22);
    T[3]  = (float)(r00 * dx + r01 * dy + r02 * dz);
    T[4]  = (float)(r10 * b00 + r11 * b10 + r12 * b20);
    T[5]  = (float)(r10 * b01 + r11 * b11 + r12 * b21);
    T[6]  = (float)(r10 * b02 + r11 * b12 + r12 * b22);
    T[7]  = (float)(r10 * dx + r11 * dy + r12 * dz);
    T[8]  = (float)(r20 * b00 + r21 * b10 + r22 * b20);
    T[9]  = (float)(r20 * b01 + r21 * b11 + r22 * b21);
    T[10] = (float)(r20 * b02 + r21 * b12 + r22 * b22);
    T[11] = (float)(r20 * dx + r21 * dy + r22 * dz);
}

// f32 transform (exact for identity rotation), f32 voxelize with *10.0f scale.
__device__ __forceinline__ void voxelize_xyz(float x, float y, float z,
                                             const float* __restrict__ T, // or nullptr
                                             float& px, float& py,
                                             int& ix, int& iy, bool& valid) {
    if (T) {
        float nx = T[0] * x + T[1] * y + T[2] * z + T[3];
        float ny = T[4] * x + T[5] * y + T[6] * z + T[7];
        float nz = T[8] * x + T[9] * y + T[10] * z + T[11];
        x = nx; y = ny; z = nz;
    }
    px = (x - 0.0f) * 10.0f;
    py = (y - (-25.6f)) * 10.0f;
    ix = (int)floorf(px);
    iy = (int)floorf(py);
    valid = (ix >= 0) & (ix < GH) & (iy >= 0) & (iy < GW) &
            (z >= -3.0f) & (z < 3.0f);
}

// Cooperative heat kernel. Grid must be 2*B*NSTRIP = 512 blocks (B=8):
// co-resident at 2 blocks/CU (40.2KB LDS, 4 waves/block).
__global__ __launch_bounds__(256, 2)
void heat_coop_kernel(const float* __restrict__ radar0,
                      const float* __restrict__ radar1,
                      const float* __restrict__ pose0,
                      const float* __restrict__ pose1,
                      float2* __restrict__ ppxy,
                      float* __restrict__ heat0,
                      float* __restrict__ heat1,
                      int B, int M) {
    cg::grid_group grid = cg::this_grid();

    __shared__ int strip[SH * GW];   // 32 KB
    __shared__ float2 sp[SCAP];      // 8 KB
    __shared__ float Tsh[8][12];
    __shared__ int sn;

    const int tid = threadIdx.x;
    const int blk = blockIdx.x;
    const int nblk = gridDim.x;
    const int BM = B * M;

    if (tid < B) compute_pose(pose0 + tid * 16, pose1 + tid * 16, &Tsh[tid][0]);
    if (tid == 0) sn = 0;
    {
        const int4 z4 = make_int4(0, 0, 0, 0);
        for (int c4 = tid * 4; c4 < SH * GW; c4 += 1024)
            *reinterpret_cast<int4*>(&strip[c4]) = z4;
    }
    __syncthreads();

    // ---- Phase 0: pre-transform all points once -> (px,py), sentinel -1e9 ----
    for (int t = blk * 256 + tid; t < 2 * BM; t += nblk * 256) {
        int map = t / BM;
        int rem = t - map * BM;
        int b = rem / M;
        const float* radar = map ? radar1 : radar0;
        const float2* pv = reinterpret_cast<const float2*>(radar + (size_t)rem * 6);
        float2 fxy = pv[0];
        float2 fzw = pv[1];
        float px, py; int ix, iy; bool valid;
        voxelize_xyz(fxy.x, fxy.y, fzw.x, map ? nullptr : &Tsh[b][0],
                     px, py, ix, iy, valid);
        ppxy[t] = valid ? make_float2(px, py) : make_float2(-1e9f, -1e9f);
    }
    grid.sync();

    // ---- Phase 1: strip splat; scan pre-transformed slice (float4, 2 pts/ld) ----
    const int b = blk % B;                 // == XCD id for B=8
    const int map = (blk / B) & 1;
    const int sx = blk / (2 * B);
    const int x0 = sx << SSHIFT;

    const float4* slice4 =
        reinterpret_cast<const float4*>(ppxy + (size_t)(map * B + b) * M);
    const float xlo = (float)(x0 - RR);          // window test in float:
    const float xhi = (float)(x0 + SH - 1 + RR + 1); // [xlo, xhi) on floor(px)

    for (int i = tid; i < M / 2; i += 256) {
        float4 q = slice4[i];
        int ix0 = (int)floorf(q.x);
        if (ix0 >= x0 - RR && ix0 <= x0 + SH - 1 + RR) {
            int slot = atomicAdd(&sn, 1);
            if (slot < SCAP) sp[slot] = make_float2(q.x, q.y);
        }
        int ix1 = (int)floorf(q.z);
        if (ix1 >= x0 - RR && ix1 <= x0 + SH - 1 + RR) {
            int slot = atomicAdd(&sn, 1);
            if (slot < SCAP) sp[slot] = make_float2(q.z, q.w);
        }
    }
    __syncthreads();

    int n = sn; if (n > SCAP) n = SCAP;
    const int total = n * 49;
    for (int t = tid; t < total; t += 256) {
        int pi = t / 49;
        int c = t - pi * 49;
        float px = sp[pi].x;
        float py = sp[pi].y;
        int ix = (int)floorf(px);
        int iy = (int)floorf(py);
        int dx = c / 7 - RR;
        int dy = c - (c / 7) * 7 - RR;
        int gx = ix + dx, gy = iy + dy;
        if (gx < x0 || gx >= x0 + SH || gy < 0 || gy >= GW) continue;
        float ddx = ((float)gx + 0.5f) - px;
        float ddy = ((float)gy + 0.5f) - py;
        float d2 = ddx * ddx + ddy * ddy;
        float val = expf(-d2 / 4.5f);
        atomicMax(&strip[(gx - x0) * GW + gy], __float_as_int(val));
    }
    __syncthreads();

    float* heat = map ? heat1 : heat0;
    float* hb = heat + (size_t)b * GHW + (size_t)x0 * GW;
    for (int c4 = tid * 4; c4 < SH * GW; c4 += 1024) {
        int4 iv = *reinterpret_cast<const int4*>(&strip[c4]);
        float4 fv;
        fv.x = __int_as_float(iv.x);
        fv.y = __int_as_float(iv.y);
        fv.z = __int_as_float(iv.z);
        fv.w = __int_as_float(iv.w);
        *reinterpret_cast<float4*>(hb + c4) = fv;
    }
    (void)xlo; (void)xhi;
}

// Fused gather, XCD-swizzled: blockIdx.x == b so linear block id % 8 == b
// (8 XCDs) -> each XCD's L2 holds its batch's heat0+heat1 (2 MB). 8 row
// elements per thread for memory-level parallelism; nontemporal loads/stores
// for streamed point/out data keep L2 for heat. row_len = 2048*264 exactly.
__global__ __launch_bounds__(256)
void gather_fused_kernel(const float* __restrict__ pc0,
                         const float* __restrict__ pc1,
                         const float* __restrict__ radar0,
                         const float* __restrict__ radar1,
                         const float* __restrict__ pose0,
                         const float* __restrict__ pose1,
                         const float* __restrict__ heat0,
                         const float* __restrict__ heat1,
                         float* __restrict__ out,
                         int N, int M) {
    __shared__ float Tsh[12];
    const int row_len = 2 * N + 2 * M;
    const int b = blockIdx.x;
    const int base = blockIdx.y * 2048 + threadIdx.x;

    if (threadIdx.x == 0) compute_pose(pose0 + b * 16, pose1 + b * 16, Tsh);
    __syncthreads();

    const float* hb0 = heat0 + (size_t)b * GHW;
    const float* hb1 = heat1 + (size_t)b * GHW;
    const float* Tb = Tsh;

    float xs[8], ys[8], zs[8];
    const float* Ts[8];
    const float* hbs[8];
    bool live[8];

    #pragma unroll
    for (int k = 0; k < 8; k++) {
        int r = base + k * 256;
        live[k] = (r < row_len);
        if (!live[k]) continue;
        const float* p;
        const float* T = nullptr;
        const float* hb;
        if (r < N) {
            p = pc0 + ((size_t)b * N + r) * 3;
            T = Tb;
            hb = hb0;
        } else if (r < N + M) {
            p = radar0 + ((size_t)b * M + (r - N)) * 6;
            T = Tb;
            hb = hb0;
        } else if (r < 2 * N + M) {
            p = pc1 + ((size_t)b * N + (r - N - M)) * 3;
            hb = hb1;
        } else {
            p = radar1 + ((size_t)b * M + (r - 2 * N - M)) * 6;
            hb = hb1;
        }
        xs[k] = __builtin_nontemporal_load(p + 0);
        ys[k] = __builtin_nontemporal_load(p + 1);
        zs[k] = __builtin_nontemporal_load(p + 2);
        Ts[k] = T;
        hbs[k] = hb;
    }

    float v[8];
    #pragma unroll
    for (int k = 0; k < 8; k++) {
        if (!live[k]) continue;
        float px, py; int ix, iy; bool valid;
        voxelize_xyz(xs[k], ys[k], zs[k], Ts[k], px, py, ix, iy, valid);
        v[k] = 0.0f;
        if (valid) v[k] = hbs[k][ix * GW + iy];
    }

    #pragma unroll
    for (int k = 0; k < 8; k++) {
        if (!live[k]) continue;
        int r = base + k * 256;
        __builtin_nontemporal_store(v[k], out + (size_t)b * row_len + r);
    }
}

extern "C" void kernel_launch(void* const* d_in, const int* in_sizes, int n_in,
                              void* d_out, int out_size, void* d_ws, size_t ws_size,
                              hipStream_t stream) {
    const float* pc0      = (const float*)d_in[0];
    const float* pc1      = (const float*)d_in[1];
    const float* radar0   = (const float*)d_in[2];
    const float* radar1   = (const float*)d_in[3];
    const float* pose0    = (const float*)d_in[4];
    const float* pose1    = (const float*)d_in[5];
    float* out = (float*)d_out;

    int B = in_sizes[4] / 16;
    int N = in_sizes[0] / (B * 3);
    int M = in_sizes[2] / (B * 6);
    int row_len = 2 * N + 2 * M;

    // workspace layout: heatmaps + pre-transformed (px,py)
    float* heat0 = (float*)d_ws;
    float* heat1 = heat0 + (size_t)B * GHW;
    float2* ppxy = (float2*)(heat1 + (size_t)B * GHW);  // 2*B*M float2 = 16MB

    int nblk = 2 * B * NSTRIP;   // 512 for B=8 (co-resident: 2/CU)
    void* args[] = {
        (void*)&radar0, (void*)&radar1, (void*)&pose0, (void*)&pose1,
        (void*)&ppxy, (void*)&heat0, (void*)&heat1, (void*)&B, (void*)&M
    };
    hipLaunchCooperativeKernel((const void*)heat_coop_kernel,
                               dim3(nblk), dim3(256), args, 0, stream);

    dim3 ggrid(B, (row_len + 2047) / 2048);
    gather_fused_kernel<<<ggrid, 256, 0, stream>>>(
        pc0, pc1, radar0, radar1, pose0, pose1, heat0, heat1, out, N, M);
}

// Round 5
// 144.834 us; speedup vs baseline: 1.4696x; 1.4696x over previous
//
#include <hip/hip_runtime.h>
#include <math.h>

// Grid constants from the reference
#define GH 512
#define GW 512
#define GHW (GH * GW)
#define RR 3
#define SH 32            // strip height (rows of the heat grid per block)
#define SSHIFT 5
#define NSTRIP (GH / SH) // 16
#define SCAP 1024        // per-strip staged capacity (mean ~608, 4-sigma ~703)
#define THR 1024         // threads per heat block (16 waves)

// Precision model (validated rounds 4-8, absmax 3.9e-3): pure f32 chain with
// multiply-by-reciprocal voxel scale (px = (x - XMIN) * 10.0f) and f32 expf.
// Do not change this arithmetic. Heatmap max is order-free (monotone int-bit
// compare on positive floats), so strip decomposition cannot perturb it.
//
// Cost model (fitted R0-R4, residual <1us on R0/R1/R3):
//   T = 21us fixed + 41us ws-poison fill + sum(device) + 13us * n_dispatch
// => minimize device time at the minimum dispatch count (2). Cooperative
// launch adds ~30-40us on top (R2, R4) - never use it here. Gather must
// stay its own fully-occupied dispatch (R2 lesson).
//
// R5: heat kernel re-parallelized, algorithm unchanged from R3:
//  - SH=32 -> 256 blocks x 1024 threads: 1 block/CU, 16 waves/CU (~50% occ
//    ceiling vs R3's grid-starved 2 blocks/CU = 16.5%); per-thread scan is
//    8 serial iterations (R3: 32); total scan redundancy 4x lower than R3.
//  - early-x reject: only 3 fma + floor for the ~93% of points outside the
//    strip's dilated row window; staged set identical.
//  - b == blk % 8 keeps each batch's radar + heat XCD-L2-local.

__device__ __forceinline__ void compute_pose(const float* __restrict__ P0,
                                             const float* __restrict__ P1,
                                             float* __restrict__ T) {
    double a00 = P1[0], a01 = P1[1], a02 = P1[2],  t1x = P1[3];
    double a10 = P1[4], a11 = P1[5], a12 = P1[6],  t1y = P1[7];
    double a20 = P1[8], a21 = P1[9], a22 = P1[10], t1z = P1[11];
    double c00 = a11 * a22 - a12 * a21;
    double c01 = a12 * a20 - a10 * a22;
    double c02 = a10 * a21 - a11 * a20;
    double det = a00 * c00 + a01 * c01 + a02 * c02;
    double id = 1.0 / det;
    double r00 = c00 * id;
    double r01 = (a02 * a21 - a01 * a22) * id;
    double r02 = (a01 * a12 - a02 * a11) * id;
    double r10 = c01 * id;
    double r11 = (a00 * a22 - a02 * a20) * id;
    double r12 = (a02 * a10 - a00 * a12) * id;
    double r20 = c02 * id;
    double r21 = (a01 * a20 - a00 * a21) * id;
    double r22 = (a00 * a11 - a01 * a10) * id;

    double b00 = P0[0], b01 = P0[1], b02 = P0[2],  t0x = P0[3];
    double b10 = P0[4], b11 = P0[5], b12 = P0[6],  t0y = P0[7];
    double b20 = P0[8], b21 = P0[9], b22 = P0[10], t0z = P0[11];
    double dx = t0x - t1x, dy = t0y - t1y, dz = t0z - t1z;

    T[0]  = (float)(r00 * b00 + r01 * b10 + r02 * b20);
    T[1]  = (float)(r00 * b01 + r01 * b11 + r02 * b21);
    T[2]  = (float)(r00 * b02 + r01 * b12 + r02 * b22);
    T[3]  = (float)(r00 * dx + r01 * dy + r02 * dz);
    T[4]  = (float)(r10 * b00 + r11 * b10 + r12 * b20);
    T[5]  = (float)(r10 * b01 + r11 * b11 + r12 * b21);
    T[6]  = (float)(r10 * b02 + r11 * b12 + r12 * b22);
    T[7]  = (float)(r10 * dx + r11 * dy + r12 * dz);
    T[8]  = (float)(r20 * b00 + r21 * b10 + r22 * b20);
    T[9]  = (float)(r20 * b01 + r21 * b11 + r22 * b21);
    T[10] = (float)(r20 * b02 + r21 * b12 + r22 * b22);
    T[11] = (float)(r20 * dx + r21 * dy + r22 * dz);
}

// f32 transform (exact for identity rotation), f32 voxelize with *10.0f scale.
__device__ __forceinline__ void voxelize_xyz(float x, float y, float z,
                                             const float* __restrict__ T, // or nullptr
                                             float& px, float& py,
                                             int& ix, int& iy, bool& valid) {
    if (T) {
        float nx = T[0] * x + T[1] * y + T[2] * z + T[3];
        float ny = T[4] * x + T[5] * y + T[6] * z + T[7];
        float nz = T[8] * x + T[9] * y + T[10] * z + T[11];
        x = nx; y = ny; z = nz;
    }
    px = (x - 0.0f) * 10.0f;
    py = (y - (-25.6f)) * 10.0f;
    ix = (int)floorf(px);
    iy = (int)floorf(py);
    valid = (ix >= 0) & (ix < GH) & (iy >= 0) & (iy < GW) &
            (z >= -3.0f) & (z < 3.0f);
}

// One block per (strip, map, b), 1024 threads. Phase A: scan this (map,b)'s
// M radar points once with early-x reject, stage (px,py) of the ~608
// in-window points into LDS. Phase B: splat n*49 (point,cell) pairs into
// the 32x512 LDS strip with atomicMax. Phase C: float4 writeback.
__global__ __launch_bounds__(THR)
void heat_strip_kernel(const float* __restrict__ radar0,
                       const float* __restrict__ radar1,
                       const float* __restrict__ pose0,
                       const float* __restrict__ pose1,
                       float* __restrict__ heat0,
                       float* __restrict__ heat1,
                       int B, int M) {
    __shared__ int strip[SH * GW];   // 64 KB
    __shared__ float2 sp[SCAP];      // 8 KB
    __shared__ float Tsh[8][12];
    __shared__ int sn;

    const int tid = threadIdx.x;
    const int blk = blockIdx.x;
    const int b = blk % B;                 // == XCD id for B=8
    const int map = (blk / B) & 1;
    const int sx = blk / (2 * B);
    const int x0 = sx << SSHIFT;

    if (tid < B) compute_pose(pose0 + tid * 16, pose1 + tid * 16, &Tsh[tid][0]);
    if (tid == 0) sn = 0;
    {
        const int4 z4 = make_int4(0, 0, 0, 0);
        for (int c4 = tid * 4; c4 < SH * GW; c4 += 4 * THR)
            *reinterpret_cast<int4*>(&strip[c4]) = z4;
    }
    __syncthreads();

    const float* radar = map ? radar1 : radar0;
    const float* pb = radar + (size_t)b * M * 6;
    const bool hasT = (map == 0);
    const float* T = &Tsh[b][0];

    // ---- Phase A: scan with early-x reject (staged set identical to R3) ----
    for (int i = tid; i < M; i += THR) {
        const float* p = pb + (size_t)i * 6;
        float x = p[0], y = p[1], z = p[2];
        float nx = hasT ? (T[0] * x + T[1] * y + T[2] * z + T[3]) : x;
        float px = (nx - 0.0f) * 10.0f;
        int ix = (int)floorf(px);
        if (ix < x0 - RR || ix > x0 + SH - 1 + RR) continue;
        float ny = hasT ? (T[4] * x + T[5] * y + T[6] * z + T[7]) : y;
        float nz = hasT ? (T[8] * x + T[9] * y + T[10] * z + T[11]) : z;
        float py = (ny - (-25.6f)) * 10.0f;
        int iy = (int)floorf(py);
        bool valid = (ix >= 0) & (ix < GH) & (iy >= 0) & (iy < GW) &
                     (nz >= -3.0f) & (nz < 3.0f);
        if (!valid) continue;
        int slot = atomicAdd(&sn, 1);
        if (slot < SCAP) sp[slot] = make_float2(px, py);
    }
    __syncthreads();

    // ---- Phase B: splat ----
    int n = sn; if (n > SCAP) n = SCAP;
    const int total = n * 49;
    for (int t = tid; t < total; t += THR) {
        int pi = t / 49;
        int c = t - pi * 49;
        float px = sp[pi].x;
        float py = sp[pi].y;
        int ix = (int)floorf(px);
        int iy = (int)floorf(py);
        int dx = c / 7 - RR;
        int dy = c - (c / 7) * 7 - RR;
        int gx = ix + dx, gy = iy + dy;
        if (gx < x0 || gx >= x0 + SH || gy < 0 || gy >= GW) continue;
        float ddx = ((float)gx + 0.5f) - px;
        float ddy = ((float)gy + 0.5f) - py;
        float d2 = ddx * ddx + ddy * ddy;
        float val = expf(-d2 / 4.5f);
        atomicMax(&strip[(gx - x0) * GW + gy], __float_as_int(val));
    }
    __syncthreads();

    // ---- Phase C: writeback ----
    float* heat = map ? heat1 : heat0;
    float* hb = heat + (size_t)b * GHW + (size_t)x0 * GW;
    for (int c4 = tid * 4; c4 < SH * GW; c4 += 4 * THR) {
        int4 iv = *reinterpret_cast<const int4*>(&strip[c4]);
        float4 fv;
        fv.x = __int_as_float(iv.x);
        fv.y = __int_as_float(iv.y);
        fv.z = __int_as_float(iv.z);
        fv.w = __int_as_float(iv.w);
        *reinterpret_cast<float4*>(hb + c4) = fv;
    }
}

// Fused gather, XCD-swizzled: blockIdx.x == b so linear block id % 8 == b
// (8 XCDs) -> each XCD's L2 holds its batch's heat0+heat1 (2 MB). 8 row
// elements per thread for memory-level parallelism; nontemporal loads/stores
// for streamed point/out data keep L2 for heat. row_len = 2048*264 exactly.
__global__ __launch_bounds__(256)
void gather_fused_kernel(const float* __restrict__ pc0,
                         const float* __restrict__ pc1,
                         const float* __restrict__ radar0,
                         const float* __restrict__ radar1,
                         const float* __restrict__ pose0,
                         const float* __restrict__ pose1,
                         const float* __restrict__ heat0,
                         const float* __restrict__ heat1,
                         float* __restrict__ out,
                         int N, int M) {
    __shared__ float Tsh[12];
    const int row_len = 2 * N + 2 * M;
    const int b = blockIdx.x;
    const int base = blockIdx.y * 2048 + threadIdx.x;

    if (threadIdx.x == 0) compute_pose(pose0 + b * 16, pose1 + b * 16, Tsh);
    __syncthreads();

    const float* hb0 = heat0 + (size_t)b * GHW;
    const float* hb1 = heat1 + (size_t)b * GHW;
    const float* Tb = Tsh;

    float xs[8], ys[8], zs[8];
    const float* Ts[8];
    const float* hbs[8];
    bool live[8];

    #pragma unroll
    for (int k = 0; k < 8; k++) {
        int r = base + k * 256;
        live[k] = (r < row_len);
        if (!live[k]) continue;
        const float* p;
        const float* T = nullptr;
        const float* hb;
        if (r < N) {
            p = pc0 + ((size_t)b * N + r) * 3;
            T = Tb;
            hb = hb0;
        } else if (r < N + M) {
            p = radar0 + ((size_t)b * M + (r - N)) * 6;
            T = Tb;
            hb = hb0;
        } else if (r < 2 * N + M) {
            p = pc1 + ((size_t)b * N + (r - N - M)) * 3;
            hb = hb1;
        } else {
            p = radar1 + ((size_t)b * M + (r - 2 * N - M)) * 6;
            hb = hb1;
        }
        xs[k] = __builtin_nontemporal_load(p + 0);
        ys[k] = __builtin_nontemporal_load(p + 1);
        zs[k] = __builtin_nontemporal_load(p + 2);
        Ts[k] = T;
        hbs[k] = hb;
    }

    float v[8];
    #pragma unroll
    for (int k = 0; k < 8; k++) {
        if (!live[k]) continue;
        float px, py; int ix, iy; bool valid;
        voxelize_xyz(xs[k], ys[k], zs[k], Ts[k], px, py, ix, iy, valid);
        v[k] = 0.0f;
        if (valid) v[k] = hbs[k][ix * GW + iy];
    }

    #pragma unroll
    for (int k = 0; k < 8; k++) {
        if (!live[k]) continue;
        int r = base + k * 256;
        __builtin_nontemporal_store(v[k], out + (size_t)b * row_len + r);
    }
}

extern "C" void kernel_launch(void* const* d_in, const int* in_sizes, int n_in,
                              void* d_out, int out_size, void* d_ws, size_t ws_size,
                              hipStream_t stream) {
    const float* pc0      = (const float*)d_in[0];
    const float* pc1      = (const float*)d_in[1];
    const float* radar0   = (const float*)d_in[2];
    const float* radar1   = (const float*)d_in[3];
    const float* pose0    = (const float*)d_in[4];
    const float* pose1    = (const float*)d_in[5];
    float* out = (float*)d_out;

    int B = in_sizes[4] / 16;
    int N = in_sizes[0] / (B * 3);
    int M = in_sizes[2] / (B * 6);
    int row_len = 2 * N + 2 * M;

    // workspace layout: just the two heatmaps
    float* heat0 = (float*)d_ws;
    float* heat1 = heat0 + (size_t)B * GHW;

    int nblk = 2 * B * NSTRIP;   // 256 for B=8: exactly 1 block/CU
    heat_strip_kernel<<<nblk, THR, 0, stream>>>(
        radar0, radar1, pose0, pose1, heat0, heat1, B, M);

    dim3 ggrid(B, (row_len + 2047) / 2048);
    gather_fused_kernel<<<ggrid, 256, 0, stream>>>(
        pc0, pc1, radar0, radar1, pose0, pose1, heat0, heat1, out, N, M);
}

// Round 6
// 142.378 us; speedup vs baseline: 1.4950x; 1.0172x over previous
//
#include <hip/hip_runtime.h>
#include <math.h>

// Grid constants from the reference
#define GH 512
#define GW 512
#define GHW (GH * GW)
#define RR 3
#define SH 32            // strip height (rows of the heat grid per block)
#define SSHIFT 5
#define NSTRIP (GH / SH) // 16
#define SCAP 1024        // per-strip staged capacity (mean ~608, 4-sigma ~703)
#define THR 1024         // threads per heat block (16 waves)
#define GCHUNK 1024      // gather: elements per block (256 thr x 4)

// Precision model (validated, absmax 3.9e-3): pure f32 chain with
// multiply-by-reciprocal voxel scale (px = (x - XMIN) * 10.0f) and f32 expf.
// Do not change this arithmetic. Heatmap max is order-free (monotone int-bit
// compare on positive floats), so strip decomposition / staging order cannot
// perturb the result.
//
// Cost model (fitted R0-R5, residual <1us on R0/R1/R3/R5):
//   T = 21us fixed + 41us ws-poison fill + sum(device) + 13us * n_dispatch
// => 2 dispatches, minimize device time. Cooperative launch adds ~30-40us
// (R2, R4) - never. R5 post-mortem: gather was 28.6us in EVERY round because
// its grid was 264 blocks = 4 waves/CU (occupancy-starved at 2.6 TB/s for
// 74MB traffic). R6: gather grid (B, 528) = 4224 blocks, 4 elems/thread.
// Heat: wave-aggregated LDS slot allocation (1 atomic/wave vs ~608
// serialized same-address atomicAdds per block).

__device__ __forceinline__ void compute_pose(const float* __restrict__ P0,
                                             const float* __restrict__ P1,
                                             float* __restrict__ T) {
    double a00 = P1[0], a01 = P1[1], a02 = P1[2],  t1x = P1[3];
    double a10 = P1[4], a11 = P1[5], a12 = P1[6],  t1y = P1[7];
    double a20 = P1[8], a21 = P1[9], a22 = P1[10], t1z = P1[11];
    double c00 = a11 * a22 - a12 * a21;
    double c01 = a12 * a20 - a10 * a22;
    double c02 = a10 * a21 - a11 * a20;
    double det = a00 * c00 + a01 * c01 + a02 * c02;
    double id = 1.0 / det;
    double r00 = c00 * id;
    double r01 = (a02 * a21 - a01 * a22) * id;
    double r02 = (a01 * a12 - a02 * a11) * id;
    double r10 = c01 * id;
    double r11 = (a00 * a22 - a02 * a20) * id;
    double r12 = (a02 * a10 - a00 * a12) * id;
    double r20 = c02 * id;
    double r21 = (a01 * a20 - a00 * a21) * id;
    double r22 = (a00 * a11 - a01 * a10) * id;

    double b00 = P0[0], b01 = P0[1], b02 = P0[2],  t0x = P0[3];
    double b10 = P0[4], b11 = P0[5], b12 = P0[6],  t0y = P0[7];
    double b20 = P0[8], b21 = P0[9], b22 = P0[10], t0z = P0[11];
    double dx = t0x - t1x, dy = t0y - t1y, dz = t0z - t1z;

    T[0]  = (float)(r00 * b00 + r01 * b10 + r02 * b20);
    T[1]  = (float)(r00 * b01 + r01 * b11 + r02 * b21);
    T[2]  = (float)(r00 * b02 + r01 * b12 + r02 * b22);
    T[3]  = (float)(r00 * dx + r01 * dy + r02 * dz);
    T[4]  = (float)(r10 * b00 + r11 * b10 + r12 * b20);
    T[5]  = (float)(r10 * b01 + r11 * b11 + r12 * b21);
    T[6]  = (float)(r10 * b02 + r11 * b12 + r12 * b22);
    T[7]  = (float)(r10 * dx + r11 * dy + r12 * dz);
    T[8]  = (float)(r20 * b00 + r21 * b10 + r22 * b20);
    T[9]  = (float)(r20 * b01 + r21 * b11 + r22 * b21);
    T[10] = (float)(r20 * b02 + r21 * b12 + r22 * b22);
    T[11] = (float)(r20 * dx + r21 * dy + r22 * dz);
}

// f32 transform (exact for identity rotation), f32 voxelize with *10.0f scale.
__device__ __forceinline__ void voxelize_xyz(float x, float y, float z,
                                             const float* __restrict__ T, // or nullptr
                                             float& px, float& py,
                                             int& ix, int& iy, bool& valid) {
    if (T) {
        float nx = T[0] * x + T[1] * y + T[2] * z + T[3];
        float ny = T[4] * x + T[5] * y + T[6] * z + T[7];
        float nz = T[8] * x + T[9] * y + T[10] * z + T[11];
        x = nx; y = ny; z = nz;
    }
    px = (x - 0.0f) * 10.0f;
    py = (y - (-25.6f)) * 10.0f;
    ix = (int)floorf(px);
    iy = (int)floorf(py);
    valid = (ix >= 0) & (ix < GH) & (iy >= 0) & (iy < GW) &
            (z >= -3.0f) & (z < 3.0f);
}

// One block per (strip, map, b), 1024 threads. Phase A: scan this (map,b)'s
// M radar points once with early-x reject, stage (px,py) of the ~608
// in-window points into LDS (wave-aggregated slot allocation). Phase B:
// splat n*49 (point,cell) pairs into the 32x512 LDS strip with atomicMax.
// Phase C: float4 writeback.
__global__ __launch_bounds__(THR)
void heat_strip_kernel(const float* __restrict__ radar0,
                       const float* __restrict__ radar1,
                       const float* __restrict__ pose0,
                       const float* __restrict__ pose1,
                       float* __restrict__ heat0,
                       float* __restrict__ heat1,
                       int B, int M) {
    __shared__ int strip[SH * GW];   // 64 KB
    __shared__ float2 sp[SCAP];      // 8 KB
    __shared__ float Tsh[8][12];
    __shared__ int sn;

    const int tid = threadIdx.x;
    const int lane = tid & 63;
    const int blk = blockIdx.x;
    const int b = blk % B;                 // == XCD id for B=8
    const int map = (blk / B) & 1;
    const int sx = blk / (2 * B);
    const int x0 = sx << SSHIFT;

    if (tid < B) compute_pose(pose0 + tid * 16, pose1 + tid * 16, &Tsh[tid][0]);
    if (tid == 0) sn = 0;
    {
        const int4 z4 = make_int4(0, 0, 0, 0);
        for (int c4 = tid * 4; c4 < SH * GW; c4 += 4 * THR)
            *reinterpret_cast<int4*>(&strip[c4]) = z4;
    }
    __syncthreads();

    const float* radar = map ? radar1 : radar0;
    const float* pb = radar + (size_t)b * M * 6;
    const bool hasT = (map == 0);
    const float* T = &Tsh[b][0];

    // ---- Phase A: scan with early-x reject; wave-aggregated staging ----
    // Loop bound uniform across the wave so __ballot is always reached.
    const int Mceil = (M + THR - 1) / THR * THR;
    for (int i0 = 0; i0 < Mceil; i0 += THR) {
        int i = i0 + tid;
        bool valid = false;
        float px = 0.0f, py = 0.0f;
        if (i < M) {
            const float* p = pb + (size_t)i * 6;
            float x = p[0], y = p[1], z = p[2];
            float nx = hasT ? (T[0] * x + T[1] * y + T[2] * z + T[3]) : x;
            px = (nx - 0.0f) * 10.0f;
            int ix = (int)floorf(px);
            if (ix >= x0 - RR && ix <= x0 + SH - 1 + RR) {
                float ny = hasT ? (T[4] * x + T[5] * y + T[6] * z + T[7]) : y;
                float nz = hasT ? (T[8] * x + T[9] * y + T[10] * z + T[11]) : z;
                py = (ny - (-25.6f)) * 10.0f;
                int iy = (int)floorf(py);
                valid = (ix >= 0) & (ix < GH) & (iy >= 0) & (iy < GW) &
                        (nz >= -3.0f) & (nz < 3.0f);
            }
        }
        unsigned long long mask = __ballot(valid);
        if (valid) {
            int leader = __ffsll((long long)mask) - 1;
            int cnt = __popcll(mask);
            int wbase = 0;
            if (lane == leader) wbase = atomicAdd(&sn, cnt);
            wbase = __shfl(wbase, leader);
            int off = __popcll(mask & ((1ull << lane) - 1ull));
            int slot = wbase + off;
            if (slot < SCAP) sp[slot] = make_float2(px, py);
        }
    }
    __syncthreads();

    // ---- Phase B: splat ----
    int n = sn; if (n > SCAP) n = SCAP;
    const int total = n * 49;
    for (int t = tid; t < total; t += THR) {
        int pi = t / 49;
        int c = t - pi * 49;
        float px = sp[pi].x;
        float py = sp[pi].y;
        int ix = (int)floorf(px);
        int iy = (int)floorf(py);
        int dx = c / 7 - RR;
        int dy = c - (c / 7) * 7 - RR;
        int gx = ix + dx, gy = iy + dy;
        if (gx < x0 || gx >= x0 + SH || gy < 0 || gy >= GW) continue;
        float ddx = ((float)gx + 0.5f) - px;
        float ddy = ((float)gy + 0.5f) - py;
        float d2 = ddx * ddx + ddy * ddy;
        float val = expf(-d2 / 4.5f);
        atomicMax(&strip[(gx - x0) * GW + gy], __float_as_int(val));
    }
    __syncthreads();

    // ---- Phase C: writeback ----
    float* heat = map ? heat1 : heat0;
    float* hb = heat + (size_t)b * GHW + (size_t)x0 * GW;
    for (int c4 = tid * 4; c4 < SH * GW; c4 += 4 * THR) {
        int4 iv = *reinterpret_cast<const int4*>(&strip[c4]);
        float4 fv;
        fv.x = __int_as_float(iv.x);
        fv.y = __int_as_float(iv.y);
        fv.z = __int_as_float(iv.z);
        fv.w = __int_as_float(iv.w);
        *reinterpret_cast<float4*>(hb + c4) = fv;
    }
}

// Fused gather, XCD-swizzled: blockIdx.x == b == linear%8 so each XCD's L2
// holds its batch's heat0+heat1 (2 MB). R6: 4 elems/thread, grid (B,528) =
// 4224 blocks (~66 waves/CU queued) - R5's 264 blocks (4 waves/CU) ran at
// 2.6 TB/s, occupancy-starved. Nontemporal loads/stores for streamed
// point/out data keep L2 for heat. row_len = 528*1024 exactly.
__global__ __launch_bounds__(256)
void gather_fused_kernel(const float* __restrict__ pc0,
                         const float* __restrict__ pc1,
                         const float* __restrict__ radar0,
                         const float* __restrict__ radar1,
                         const float* __restrict__ pose0,
                         const float* __restrict__ pose1,
                         const float* __restrict__ heat0,
                         const float* __restrict__ heat1,
                         float* __restrict__ out,
                         int N, int M) {
    __shared__ float Tsh[12];
    const int row_len = 2 * N + 2 * M;
    const int b = blockIdx.x;
    const int base = blockIdx.y * GCHUNK + threadIdx.x;

    if (threadIdx.x == 0) compute_pose(pose0 + b * 16, pose1 + b * 16, Tsh);
    __syncthreads();

    const float* hb0 = heat0 + (size_t)b * GHW;
    const float* hb1 = heat1 + (size_t)b * GHW;
    const float* Tb = Tsh;

    float xs[4], ys[4], zs[4];
    const float* Ts[4];
    const float* hbs[4];
    bool live[4];

    #pragma unroll
    for (int k = 0; k < 4; k++) {
        int r = base + k * 256;
        live[k] = (r < row_len);
        if (!live[k]) continue;
        const float* p;
        const float* T = nullptr;
        const float* hb;
        if (r < N) {
            p = pc0 + ((size_t)b * N + r) * 3;
            T = Tb;
            hb = hb0;
        } else if (r < N + M) {
            p = radar0 + ((size_t)b * M + (r - N)) * 6;
            T = Tb;
            hb = hb0;
        } else if (r < 2 * N + M) {
            p = pc1 + ((size_t)b * N + (r - N - M)) * 3;
            hb = hb1;
        } else {
            p = radar1 + ((size_t)b * M + (r - 2 * N - M)) * 6;
            hb = hb1;
        }
        xs[k] = __builtin_nontemporal_load(p + 0);
        ys[k] = __builtin_nontemporal_load(p + 1);
        zs[k] = __builtin_nontemporal_load(p + 2);
        Ts[k] = T;
        hbs[k] = hb;
    }

    float v[4];
    #pragma unroll
    for (int k = 0; k < 4; k++) {
        if (!live[k]) continue;
        float px, py; int ix, iy; bool valid;
        voxelize_xyz(xs[k], ys[k], zs[k], Ts[k], px, py, ix, iy, valid);
        v[k] = 0.0f;
        if (valid) v[k] = hbs[k][ix * GW + iy];
    }

    #pragma unroll
    for (int k = 0; k < 4; k++) {
        if (!live[k]) continue;
        int r = base + k * 256;
        __builtin_nontemporal_store(v[k], out + (size_t)b * row_len + r);
    }
}

extern "C" void kernel_launch(void* const* d_in, const int* in_sizes, int n_in,
                              void* d_out, int out_size, void* d_ws, size_t ws_size,
                              hipStream_t stream) {
    const float* pc0      = (const float*)d_in[0];
    const float* pc1      = (const float*)d_in[1];
    const float* radar0   = (const float*)d_in[2];
    const float* radar1   = (const float*)d_in[3];
    const float* pose0    = (const float*)d_in[4];
    const float* pose1    = (const float*)d_in[5];
    float* out = (float*)d_out;

    int B = in_sizes[4] / 16;
    int N = in_sizes[0] / (B * 3);
    int M = in_sizes[2] / (B * 6);
    int row_len = 2 * N + 2 * M;

    // workspace layout: just the two heatmaps
    float* heat0 = (float*)d_ws;
    float* heat1 = heat0 + (size_t)B * GHW;

    int nblk = 2 * B * NSTRIP;   // 256 for B=8: exactly 1 block/CU
    heat_strip_kernel<<<nblk, THR, 0, stream>>>(
        radar0, radar1, pose0, pose1, heat0, heat1, B, M);

    dim3 ggrid(B, (row_len + GCHUNK - 1) / GCHUNK);
    gather_fused_kernel<<<ggrid, 256, 0, stream>>>(
        pc0, pc1, radar0, radar1, pose0, pose1, heat0, heat1, out, N, M);
}